// Round 1
// 431.903 us; speedup vs baseline: 1.0363x; 1.0363x over previous
//
#include <hip/hip_runtime.h>
#include <math.h>

// GATNet_MLP R16: rewrite gat_agg for memory-level parallelism.
//  - branch-free edge chunks (pv=0 for dup slots instead of `break`) so the
//    unrolled gather loop has no control flow and all loads stay in flight
//  - f16x8 gathers, wave split into 2x32-lane halves = 2 edges in flight;
//    halves combined once per node via shfl_xor(32)
//  - a_e precomputed per (layer, csr_pos, head) in fill_kernel (fp16) ->
//    coalesced 128B reads replace scattered 20B ea gathers + 5 FMAs/edge
//  - csr shrinks int2 -> int (edge id no longer needed at agg time)

#define N_NODES 50000
#define N_EDGES 400000
#define N_GRAPH 64
#define DIN     128
#define NHC     256
#define DOUT    32

typedef _Float16 f16x8 __attribute__((ext_vector_type(8)));
typedef _Float16 f16x4 __attribute__((ext_vector_type(4)));
typedef float    f32x4 __attribute__((ext_vector_type(4)));

#define LDP2 72   // padded LDS row stride in halfs for BK=64 (144B)

// ================= fp16 MFMA GEMM, 128x64 tile, BK=64, pipelined ==========
// mode 0: C fp16 [nrow][256]; if asl!=null also per-head a_s/a_d (C=32 layers).
// mode 3: NO C write; v=gelu(v+bias); per-graph pooled sums (batch sorted).
__global__ __launch_bounds__(256) void mfma_gemm_kernel(
    const _Float16* __restrict__ Ah, const _Float16* __restrict__ Bh,
    const float* __restrict__ bias, _Float16* __restrict__ Ch,
    const float* __restrict__ asl, const float* __restrict__ adl,
    float* __restrict__ asb, float* __restrict__ adb,
    const int* __restrict__ batch, float* __restrict__ pooled,
    int nrow, int K, int mode)
{
    __shared__ __align__(16) _Float16 sAh[128][LDP2];   // 18.4 KB
    __shared__ __align__(16) _Float16 sBh[64][LDP2];    //  9.2 KB

    const int tid = threadIdx.x, lane = tid & 63, wid = tid >> 6;
    const int wm = wid & 1, wn = wid >> 1;

    int xt, yt;
    if (gridDim.x == 4) {
        int bid = blockIdx.x + (blockIdx.y << 2);
        yt = (bid >> 5) * 8 + (bid & 7);
        xt = (bid >> 3) & 3;
    } else { xt = blockIdx.x; yt = blockIdx.y; }
    const int row0 = yt * 128, col0 = xt * 64;
    if (row0 >= nrow) return;

    const int frow = lane & 15, fk = (lane >> 4) * 8;

    f32x4 acc[4][2] = {};
    f16x8 pA[4], pB[2];

    // prefetch k-tile 0
#pragma unroll
    for (int p = 0; p < 4; p++) {
        int idx = tid + p * 256;                     // 0..1023
        int r = idx >> 3, ch = (idx & 7) * 8;
        int gr = row0 + r;
        pA[p] = (gr < nrow) ? *(const f16x8*)(Ah + (long)gr * K + ch) : (f16x8)0;
    }
#pragma unroll
    for (int p = 0; p < 2; p++) {
        int idx = tid + p * 256;                     // 0..511
        int r = idx >> 3, ch = (idx & 7) * 8;
        pB[p] = *(const f16x8*)(Bh + (long)(col0 + r) * K + ch);
    }

    for (int k0 = 0; k0 < K; k0 += 64) {
#pragma unroll
        for (int p = 0; p < 4; p++) {
            int idx = tid + p * 256;
            *(f16x8*)&sAh[idx >> 3][(idx & 7) * 8] = pA[p];
        }
#pragma unroll
        for (int p = 0; p < 2; p++) {
            int idx = tid + p * 256;
            *(f16x8*)&sBh[idx >> 3][(idx & 7) * 8] = pB[p];
        }
        __syncthreads();

        if (k0 + 64 < K) {
            int kn = k0 + 64;
#pragma unroll
            for (int p = 0; p < 4; p++) {
                int idx = tid + p * 256;
                int r = idx >> 3, ch = (idx & 7) * 8;
                int gr = row0 + r;
                pA[p] = (gr < nrow) ? *(const f16x8*)(Ah + (long)gr * K + kn + ch) : (f16x8)0;
            }
#pragma unroll
            for (int p = 0; p < 2; p++) {
                int idx = tid + p * 256;
                int r = idx >> 3, ch = (idx & 7) * 8;
                pB[p] = *(const f16x8*)(Bh + (long)(col0 + r) * K + kn + ch);
            }
        }

#pragma unroll
        for (int sub = 0; sub < 2; sub++) {
            const int fks = fk + sub * 32;
            f16x8 bh[2];
#pragma unroll
            for (int nt = 0; nt < 2; nt++)
                bh[nt] = *(const f16x8*)&sBh[wn * 32 + nt * 16 + frow][fks];
#pragma unroll
            for (int mt = 0; mt < 4; mt++) {
                f16x8 ah = *(const f16x8*)&sAh[wm * 64 + mt * 16 + frow][fks];
#pragma unroll
                for (int nt = 0; nt < 2; nt++)
                    acc[mt][nt] = __builtin_amdgcn_mfma_f32_16x16x32_f16(ah, bh[nt], acc[mt][nt], 0, 0, 0);
            }
        }
        __syncthreads();
    }

    const int crow0 = row0 + wm * 64 + (lane >> 4) * 4;
    const int ccol0 = col0 + wn * 32 + (lane & 15);

    if (mode == 0) {
#pragma unroll
        for (int mt = 0; mt < 4; mt++)
#pragma unroll
            for (int nt = 0; nt < 2; nt++) {
                int col = ccol0 + nt * 16;
#pragma unroll
                for (int r = 0; r < 4; r++) {
                    int row = crow0 + mt * 16 + r;
                    if (row < nrow) Ch[(long)row * 256 + col] = (_Float16)acc[mt][nt][r];
                }
            }
        // fused a_s/a_d from fp32 acc regs (C=32 layers): plain stores.
        if (asl != nullptr) {
            const float asl0 = asl[ccol0], asl1 = asl[ccol0 + 16];
            const float adl0 = adl[ccol0], adl1 = adl[ccol0 + 16];
            const int headw = (col0 + wn * 32) >> 5;
#pragma unroll
            for (int mt = 0; mt < 4; mt++) {
#pragma unroll
                for (int r = 0; r < 4; r++) {
                    float s = acc[mt][0][r] * asl0 + acc[mt][1][r] * asl1;
                    float d = acc[mt][0][r] * adl0 + acc[mt][1][r] * adl1;
                    s += __shfl_xor(s, 1); s += __shfl_xor(s, 2);
                    s += __shfl_xor(s, 4); s += __shfl_xor(s, 8);
                    d += __shfl_xor(d, 1); d += __shfl_xor(d, 2);
                    d += __shfl_xor(d, 4); d += __shfl_xor(d, 8);
                    if ((lane & 15) == 0) {
                        int row = crow0 + mt * 16 + r;
                        if (row < nrow) {
                            asb[row * 8 + headw] = s;
                            adb[row * 8 + headw] = d;
                        }
                    }
                }
            }
        }
    } else {
        // mode 3: gelu(v+bias) -> per-graph pooled sums, register pre-accum (R11).
        float* pool = (float*)&sAh[0][0];            // 16*64 floats = 4KB
        const int g0 = batch[row0];
        const int rlast = (row0 + 127 < nrow) ? row0 + 127 : nrow - 1;
        const int gspan = batch[rlast] - g0 + 1;
        const bool fits = (gspan <= 16);
        for (int i = tid; i < 16 * 64; i += 256) pool[i] = 0.f;
        __syncthreads();

        const float b0 = bias[ccol0], b1 = bias[ccol0 + 16];
        const int lc0 = ccol0 - col0, lc1 = lc0 + 16;
        float sum0 = 0.f, sum1 = 0.f;
        int curg = -1;
#pragma unroll
        for (int mt = 0; mt < 4; mt++) {
#pragma unroll
            for (int r = 0; r < 4; r++) {
                int row = crow0 + mt * 16 + r;
                if (row >= nrow) continue;
                int g = batch[row];
                if (g != curg) {
                    if (curg >= 0) {
                        if (fits) {
                            atomicAdd(&pool[(curg - g0) * 64 + lc0], sum0);
                            atomicAdd(&pool[(curg - g0) * 64 + lc1], sum1);
                        } else {
                            atomicAdd(&pooled[curg * 256 + ccol0], sum0);
                            atomicAdd(&pooled[curg * 256 + ccol0 + 16], sum1);
                        }
                    }
                    curg = g; sum0 = 0.f; sum1 = 0.f;
                }
                float v0 = acc[mt][0][r] + b0;
                float v1 = acc[mt][1][r] + b1;
                sum0 += 0.5f * v0 * (1.f + erff(v0 * 0.7071067811865475f));
                sum1 += 0.5f * v1 * (1.f + erff(v1 * 0.7071067811865475f));
            }
        }
        if (curg >= 0) {
            if (fits) {
                atomicAdd(&pool[(curg - g0) * 64 + lc0], sum0);
                atomicAdd(&pool[(curg - g0) * 64 + lc1], sum1);
            } else {
                atomicAdd(&pooled[curg * 256 + ccol0], sum0);
                atomicAdd(&pooled[curg * 256 + ccol0 + 16], sum1);
            }
        }
        __syncthreads();
        if (fits) {
            for (int i = tid; i < gspan * 64; i += 256) {
                float val = pool[i];
                if (val != 0.f)
                    atomicAdd(&pooled[(g0 + (i >> 6)) * 256 + col0 + (i & 63)], val);
            }
        }
    }
}

// ================= single prep kernel =================
#define J0 1600000                       // x convert (float4 units): N*DIN/4
#define J1 32768                         // W1 transpose (256 x 128)
#define J2 65536                         // W2
#define J3 65536                         // W3
#define J4 65536                         // fcW1
#define J5 16384                         // zero pooled (64*256)
#define J6 N_NODES                       // zero deg
#define J7 64                            // zero gcnt
#define JTOT (J0+J1+J2+J3+J4+J5+J6+J7)

__device__ __forceinline__ void t_one(const float* W, _Float16* Bh,
                                      int id, int K, int realN)
{
    int n = id / K, k = id - n * K;
    Bh[id] = (_Float16)W[(long)k * realN + n];
}

__global__ __launch_bounds__(256) void prep_kernel(
    const float* __restrict__ x,
    const float* __restrict__ W1, const float* __restrict__ W2, const float* __restrict__ W3,
    const float* __restrict__ F1,
    _Float16* __restrict__ xh,
    _Float16* __restrict__ W1th, _Float16* __restrict__ W2th,
    _Float16* __restrict__ W3th, _Float16* __restrict__ F1th,
    float* __restrict__ pooled, int* __restrict__ deg, int* __restrict__ gcnt)
{
    int idx = blockIdx.x * 256 + threadIdx.x;
    if (idx < J0) {
        float4 v = ((const float4*)x)[idx];
        f16x4 h;
        h[0] = (_Float16)v.x; h[1] = (_Float16)v.y;
        h[2] = (_Float16)v.z; h[3] = (_Float16)v.w;
        *(f16x4*)(xh + (long)idx * 4) = h;
        return;
    }
    idx -= J0;
    if (idx < J1) { t_one(W1, W1th, idx, DIN, NHC); return; }
    idx -= J1;
    if (idx < J2) { t_one(W2, W2th, idx, NHC, NHC); return; }
    idx -= J2;
    if (idx < J3) { t_one(W3, W3th, idx, NHC, NHC); return; }
    idx -= J3;
    if (idx < J4) { t_one(F1, F1th, idx, NHC, NHC); return; }
    idx -= J4;
    if (idx < J5) { pooled[idx] = 0.f; return; }
    idx -= J5;
    if (idx < J6) { deg[idx] = 0; return; }
    idx -= J6;
    if (idx < J7) { gcnt[idx] = 0; return; }
}

// -------- all 3 layers' Me[5][H] in one launch --------
__global__ void me_all_kernel(
    const float* __restrict__ We1, const float* __restrict__ ae1,
    const float* __restrict__ We2, const float* __restrict__ ae2,
    const float* __restrict__ We3, const float* __restrict__ ae3,
    float* __restrict__ MeAll)
{
    int l = blockIdx.x;
    const float* We = (l == 0) ? We1 : (l == 1) ? We2 : We3;
    const float* ae = (l == 0) ? ae1 : (l == 1) ? ae2 : ae3;
    int H = (l == 2) ? 1 : 8, C = (l == 2) ? 256 : 32;
    int t = threadIdx.x;
    if (t >= 5 * H) return;
    int j = t / H, hh = t - j * H;
    float s = 0.f;
    for (int c = 0; c < C; c++) s += We[j * NHC + hh * C + c] * ae[hh * C + c];
    MeAll[l * 40 + j * H + hh] = s;
}

// -------- asd (layer 3 only: H=1, C=256), fp16 h --------
__global__ __launch_bounds__(256) void asd_kernel(
    const _Float16* __restrict__ h, const float* __restrict__ atts, const float* __restrict__ attd,
    float* __restrict__ asb, float* __restrict__ adb, int total)
{
    int n = blockIdx.x * 256 + threadIdx.x;
    if (n >= total) return;
    const f16x8* hp = (const f16x8*)(h + (long)n * NHC);
    const float4* sp = (const float4*)atts;
    const float4* dp = (const float4*)attd;
    float ss = 0.f, dd = 0.f;
    for (int c = 0; c < NHC / 8; c++) {
        f16x8 hv = hp[c];
        float4 s1 = sp[2 * c], s2 = sp[2 * c + 1];
        float4 d1 = dp[2 * c], d2 = dp[2 * c + 1];
        ss += (float)hv[0] * s1.x + (float)hv[1] * s1.y + (float)hv[2] * s1.z + (float)hv[3] * s1.w
            + (float)hv[4] * s2.x + (float)hv[5] * s2.y + (float)hv[6] * s2.z + (float)hv[7] * s2.w;
        dd += (float)hv[0] * d1.x + (float)hv[1] * d1.y + (float)hv[2] * d1.z + (float)hv[3] * d1.w
            + (float)hv[4] * d2.x + (float)hv[5] * d2.y + (float)hv[6] * d2.z + (float)hv[7] * d2.w;
    }
    asb[n * 8] = ss; adb[n * 8] = dd;
}

// ================= CSR build =================
__global__ __launch_bounds__(256) void count_hist_kernel(
    const int* __restrict__ ei, const int* __restrict__ batch,
    int* __restrict__ deg, int* __restrict__ gcnt, int E, int N)
{
    __shared__ int hist[N_GRAPH];
    int t = threadIdx.x;
    if (t < N_GRAPH) hist[t] = 0;
    __syncthreads();
    int i = blockIdx.x * 256 + t;
    if (i < E) atomicAdd(&deg[ei[E + i]], 1);
    if (i < N) atomicAdd(&hist[batch[i]], 1);
    __syncthreads();
    if (t < N_GRAPH && hist[t] > 0) atomicAdd(&gcnt[t], hist[t]);
}

__global__ __launch_bounds__(256) void scan_block_kernel(
    const int* __restrict__ deg, int* __restrict__ rowstart, int* __restrict__ partial, int n)
{
    __shared__ int s[256];
    int i = blockIdx.x * 256 + threadIdx.x;
    int v = (i < n) ? deg[i] : 0;
    s[threadIdx.x] = v;
    __syncthreads();
    for (int off = 1; off < 256; off <<= 1) {
        int t = (threadIdx.x >= off) ? s[threadIdx.x - off] : 0;
        __syncthreads();
        s[threadIdx.x] += t;
        __syncthreads();
    }
    if (i < n) rowstart[i] = s[threadIdx.x] - v;
    if (threadIdx.x == 255) partial[blockIdx.x] = s[255];
}

__global__ __launch_bounds__(256) void scan_partial_kernel(int* __restrict__ partial, int nb)
{
    __shared__ int s[256];
    int v = (threadIdx.x < nb) ? partial[threadIdx.x] : 0;
    s[threadIdx.x] = v;
    __syncthreads();
    for (int off = 1; off < 256; off <<= 1) {
        int t = (threadIdx.x >= off) ? s[threadIdx.x - off] : 0;
        __syncthreads();
        s[threadIdx.x] += t;
        __syncthreads();
    }
    if (threadIdx.x < nb) partial[threadIdx.x] = s[threadIdx.x] - v;
}

__global__ __launch_bounds__(256) void scan_add_kernel(
    int* __restrict__ rowstart, const int* __restrict__ partial, int* __restrict__ cursor,
    int n, int E)
{
    int i = blockIdx.x * 256 + threadIdx.x;
    if (i < n) {
        int v = rowstart[i] + partial[blockIdx.x];
        rowstart[i] = v;
        cursor[i] = v;
    }
    if (i == 0) rowstart[n] = E;
}

// fill: CSR src ids + per-(layer,pos,head) precomputed a_e (fp16, csr order).
__global__ __launch_bounds__(256) void fill_kernel(
    const int* __restrict__ ei, const float* __restrict__ ea,
    const float* __restrict__ MeAll, int* __restrict__ cursor,
    int* __restrict__ csr, _Float16* __restrict__ aec, int E)
{
    int e = blockIdx.x * 256 + threadIdx.x;
    if (e >= E) return;
    int dst = ei[E + e];
    int pos = atomicAdd(&cursor[dst], 1);
    csr[pos] = ei[e];
    const float* eap = ea + (long)e * 5;
    float e0 = eap[0], e1 = eap[1], e2 = eap[2], e3 = eap[3], e4 = eap[4];
#pragma unroll
    for (int l = 0; l < 2; l++) {
        const float* Me = MeAll + l * 40;
        f16x8 v;
#pragma unroll
        for (int hh = 0; hh < 8; hh++) {
            float s = e0 * Me[hh] + e1 * Me[8 + hh] + e2 * Me[16 + hh]
                    + e3 * Me[24 + hh] + e4 * Me[32 + hh];
            v[hh] = (_Float16)s;
        }
        *(f16x8*)(aec + (long)l * N_EDGES * 8 + (long)pos * 8) = v;
    }
    const float* Me2 = MeAll + 80;
    float s2 = e0 * Me2[0] + e1 * Me2[1] + e2 * Me2[2] + e3 * Me2[3] + e4 * Me2[4];
    f16x8 v2;
#pragma unroll
    for (int hh = 0; hh < 8; hh++) v2[hh] = (_Float16)s2;
    *(f16x8*)(aec + (long)2 * N_EDGES * 8 + (long)pos * 8) = v2;
}

// ========== fused GAT aggregation: branch-free, f16x8, 2 edges in flight ====
// wave = 1 node. Phase 1: 8 lanes/edge x 8 edges compute alpha (dups -> pv=0).
// Phase 2: halves (32 lanes) gather f16x8 rows of 2 edges concurrently;
// halves combined once at the end via shfl_xor(32).
__global__ __launch_bounds__(256) void gat_agg_kernel(
    const int* __restrict__ rowstart, const int* __restrict__ csr,
    const _Float16* __restrict__ aec, const float* __restrict__ asb,
    const float* __restrict__ adb,
    const _Float16* __restrict__ h, const float* __restrict__ bias,
    _Float16* __restrict__ Oh, int H, int clog2)
{
    int node = blockIdx.x * 4 + (threadIdx.x >> 6);
    if (node >= N_NODES) return;
    const int lane = threadIdx.x & 63;
    const int half = lane >> 5;        // which edge of the pair
    const int c8   = (lane & 31) * 8;  // this lane's 8-channel group
    const int hc   = c8 >> clog2;      // head owning the group
    const int heff = lane & (H - 1);   // head for alpha compute
    const int grp  = lane >> 3;        // edge slot 0..7 in phase 1

    const float adn = adb[node * 8 + heff];
    const int beg = rowstart[node], end = rowstart[node + 1];

    float acc[8] = {};
    float den = 0.f;

    for (int i = beg; i < end; i += 8) {
        int idx = i + grp;
        const bool valid = (idx < end);
        if (!valid) idx = end - 1;
        const int sj = csr[idx];
        const float ae = (float)aec[(long)idx * 8 + heff];
        float al = asb[sj * 8 + heff] + adn + ae;
        al = fmaxf(al, 0.2f * al);
        const float pv = valid ? expf(al) : 0.f;
#pragma unroll
        for (int jj = 0; jj < 4; jj++) {
            const int j = jj * 2 + half;
            const float pj = __shfl(pv, j * 8 + hc);
            const int srcj = __shfl(sj, j * 8);
            const f16x8 hv = *(const f16x8*)(h + (long)srcj * NHC + c8);
            den += pj;
#pragma unroll
            for (int k = 0; k < 8; k++)
                acc[k] += pj * (float)hv[k];
        }
    }

    den += __shfl_xor(den, 32);
#pragma unroll
    for (int k = 0; k < 8; k++)
        acc[k] += __shfl_xor(acc[k], 32);

    if (half == 0) {
        const float w = 1.0f / (den + 1e-16f);
        const float4 b0 = *(const float4*)(bias + c8);
        const float4 b1 = *(const float4*)(bias + c8 + 4);
        const float bb[8] = {b0.x, b0.y, b0.z, b0.w, b1.x, b1.y, b1.z, b1.w};
        f16x8 oh;
#pragma unroll
        for (int k = 0; k < 8; k++) {
            float v = acc[k] * w + bb[k];
            v = (v > 0.f) ? v : expm1f(v);
            oh[k] = (_Float16)v;
        }
        *(f16x8*)(Oh + (long)node * NHC + c8) = oh;
    }
}

// ================= final: out[g,:] = (pooled[g,:]@fcW2)/cnt + fcb2 =================
__global__ void final_kernel(const float* __restrict__ pooled, const int* __restrict__ gcnt,
                             const float* __restrict__ fcW2, const float* __restrict__ fcb2,
                             float* __restrict__ out)
{
    int g = blockIdx.x;
    int j = threadIdx.x;
    if (j >= DOUT) return;
    float s = 0.f;
    for (int k = 0; k < NHC; k++) s += pooled[g * NHC + k] * fcW2[k * DOUT + j];
    int c = gcnt[g];
    out[g * DOUT + j] = (c > 0) ? (s / (float)c + fcb2[j]) : 0.f;
}

extern "C" void kernel_launch(void* const* d_in, const int* in_sizes, int n_in,
                              void* d_out, int out_size, void* d_ws, size_t ws_size,
                              hipStream_t stream)
{
    const float* x    = (const float*)d_in[0];
    const int*   ei   = (const int*)  d_in[1];
    const float* ea   = (const float*)d_in[2];
    const int*   bat  = (const int*)  d_in[3];
    const float* W[3]   = {(const float*)d_in[4],  (const float*)d_in[10], (const float*)d_in[16]};
    const float* Asl[3] = {(const float*)d_in[5],  (const float*)d_in[11], (const float*)d_in[17]};
    const float* Adl[3] = {(const float*)d_in[6],  (const float*)d_in[12], (const float*)d_in[18]};
    const float* Wel[3] = {(const float*)d_in[7],  (const float*)d_in[13], (const float*)d_in[19]};
    const float* Ael[3] = {(const float*)d_in[8],  (const float*)d_in[14], (const float*)d_in[20]};
    const float* Bil[3] = {(const float*)d_in[9],  (const float*)d_in[15], (const float*)d_in[21]};
    const float* fcW1 = (const float*)d_in[22];
    const float* fcb1 = (const float*)d_in[23];
    const float* fcW2 = (const float*)d_in[24];
    const float* fcb2 = (const float*)d_in[25];

    // ---- workspace carve (bytes) ----
    char* w = (char*)d_ws;
    _Float16* h    = (_Float16*)w;     w += (size_t)N_NODES * NHC * 2;   // fp16 h
    _Float16* xh   = (_Float16*)w;     w += (size_t)N_NODES * DIN * 2;
    _Float16* xbh  = (_Float16*)w;     w += (size_t)N_NODES * NHC * 2;
    float*    asb  = (float*)w;        w += (size_t)N_NODES * 8 * 4;
    float*    adb  = (float*)w;        w += (size_t)N_NODES * 8 * 4;
    float*    MeAll= (float*)w;        w += 120 * 4;
    float*    pooled=(float*)w;        w += (size_t)N_GRAPH * NHC * 4;
    _Float16* W1th = (_Float16*)w;     w += (size_t)NHC * DIN * 2;
    _Float16* W2th = (_Float16*)w;     w += (size_t)NHC * NHC * 2;
    _Float16* W3th = (_Float16*)w;     w += (size_t)NHC * NHC * 2;
    _Float16* F1th = (_Float16*)w;     w += (size_t)NHC * NHC * 2;
    int* gcnt     = (int*)w;           w += N_GRAPH * 4;
    int* deg      = (int*)w;           w += (size_t)N_NODES * 4;
    int* rowstart = (int*)w;           w += (size_t)(N_NODES + 1) * 4;
    int* cursor   = (int*)w;           w += (size_t)N_NODES * 4;
    int* partial  = (int*)w;           w += 256 * 4;
    w = (char*)(((size_t)w + 15) & ~(size_t)15);
    int* csr      = (int*)w;           w += (size_t)N_EDGES * 4;
    w = (char*)(((size_t)w + 15) & ~(size_t)15);
    _Float16* aec = (_Float16*)w;      w += (size_t)3 * N_EDGES * 8 * 2;  // 19.2 MB

    const int NB = (N_NODES + 255) / 256;

    prep_kernel<<<(JTOT + 255) / 256, 256, 0, stream>>>(
        x, W[0], W[1], W[2], fcW1,
        xh, W1th, W2th, W3th, F1th,
        pooled, deg, gcnt);
    count_hist_kernel<<<(N_EDGES + 255) / 256, 256, 0, stream>>>(ei, bat, deg, gcnt, N_EDGES, N_NODES);
    scan_block_kernel<<<NB, 256, 0, stream>>>(deg, rowstart, partial, N_NODES);
    scan_partial_kernel<<<1, 256, 0, stream>>>(partial, NB);
    scan_add_kernel<<<NB, 256, 0, stream>>>(rowstart, partial, cursor, N_NODES, N_EDGES);
    me_all_kernel<<<3, 64, 0, stream>>>(Wel[0], Ael[0], Wel[1], Ael[1], Wel[2], Ael[2], MeAll);
    fill_kernel<<<(N_EDGES + 255) / 256, 256, 0, stream>>>(ei, ea, MeAll, cursor, csr, aec, N_EDGES);

    const int Hs[3] = {8, 8, 1};
    const int CL[3] = {5, 5, 8};
    const int Ks[3] = {DIN, NHC, NHC};

    const dim3 ggrid(4, 392);

    const _Float16* curh = xh;
    const _Float16* Wth[3] = {W1th, W2th, W3th};
    for (int l = 0; l < 3; l++) {
        const int H = Hs[l];
        const bool fuse = (l != 2);
        mfma_gemm_kernel<<<ggrid, 256, 0, stream>>>(
            curh, Wth[l], nullptr, h,
            fuse ? Asl[l] : nullptr, fuse ? Adl[l] : nullptr, asb, adb,
            nullptr, nullptr,
            N_NODES, Ks[l], 0);
        if (!fuse)
            asd_kernel<<<(N_NODES + 255) / 256, 256, 0, stream>>>(
                h, Asl[l], Adl[l], asb, adb, N_NODES);
        gat_agg_kernel<<<(N_NODES + 3) / 4, 256, 0, stream>>>(
            rowstart, csr, aec + (size_t)l * N_EDGES * 8, asb, adb, h, Bil[l], xbh, H, CL[l]);
        curh = xbh;
    }

    // fc1 + fused gelu + per-graph pooling (fc2 commutes with pooling)
    mfma_gemm_kernel<<<ggrid, 256, 0, stream>>>(
        xbh, F1th, fcb1, nullptr,
        nullptr, nullptr, nullptr, nullptr,
        bat, pooled,
        N_NODES, NHC, 3);
    final_kernel<<<N_GRAPH, 64, 0, stream>>>(pooled, gcnt, fcW2, fcb2, (float*)d_out);
}

// Round 2
// 428.194 us; speedup vs baseline: 1.0453x; 1.0087x over previous
//
#include <hip/hip_runtime.h>
#include <math.h>

// GATNet_MLP R17:
//  - fill split: fill writes only csr2 (8B scatter); new aec_kernel is
//    coalesced-per-pos (scattered READS pipeline, scattered writes don't).
//    R16's fused fill was 51us at 1.3% VALUBusy = scattered-write latency.
//  - gat_agg: expf/expm1f -> __expf (output is fp16, eps 5e-4 >> fast-exp err).
//    R16 showed VALUBusy 72% = instruction-count-bound, libm exp is ~25 instrs.

#define N_NODES 50000
#define N_EDGES 400000
#define N_GRAPH 64
#define DIN     128
#define NHC     256
#define DOUT    32

typedef _Float16 f16x8 __attribute__((ext_vector_type(8)));
typedef _Float16 f16x4 __attribute__((ext_vector_type(4)));
typedef float    f32x4 __attribute__((ext_vector_type(4)));

#define LDP2 72   // padded LDS row stride in halfs for BK=64 (144B)

// ================= fp16 MFMA GEMM, 128x64 tile, BK=64, pipelined ==========
// mode 0: C fp16 [nrow][256]; if asl!=null also per-head a_s/a_d (C=32 layers).
// mode 3: NO C write; v=gelu(v+bias); per-graph pooled sums (batch sorted).
__global__ __launch_bounds__(256) void mfma_gemm_kernel(
    const _Float16* __restrict__ Ah, const _Float16* __restrict__ Bh,
    const float* __restrict__ bias, _Float16* __restrict__ Ch,
    const float* __restrict__ asl, const float* __restrict__ adl,
    float* __restrict__ asb, float* __restrict__ adb,
    const int* __restrict__ batch, float* __restrict__ pooled,
    int nrow, int K, int mode)
{
    __shared__ __align__(16) _Float16 sAh[128][LDP2];   // 18.4 KB
    __shared__ __align__(16) _Float16 sBh[64][LDP2];    //  9.2 KB

    const int tid = threadIdx.x, lane = tid & 63, wid = tid >> 6;
    const int wm = wid & 1, wn = wid >> 1;

    int xt, yt;
    if (gridDim.x == 4) {
        int bid = blockIdx.x + (blockIdx.y << 2);
        yt = (bid >> 5) * 8 + (bid & 7);
        xt = (bid >> 3) & 3;
    } else { xt = blockIdx.x; yt = blockIdx.y; }
    const int row0 = yt * 128, col0 = xt * 64;
    if (row0 >= nrow) return;

    const int frow = lane & 15, fk = (lane >> 4) * 8;

    f32x4 acc[4][2] = {};
    f16x8 pA[4], pB[2];

    // prefetch k-tile 0
#pragma unroll
    for (int p = 0; p < 4; p++) {
        int idx = tid + p * 256;                     // 0..1023
        int r = idx >> 3, ch = (idx & 7) * 8;
        int gr = row0 + r;
        pA[p] = (gr < nrow) ? *(const f16x8*)(Ah + (long)gr * K + ch) : (f16x8)0;
    }
#pragma unroll
    for (int p = 0; p < 2; p++) {
        int idx = tid + p * 256;                     // 0..511
        int r = idx >> 3, ch = (idx & 7) * 8;
        pB[p] = *(const f16x8*)(Bh + (long)(col0 + r) * K + ch);
    }

    for (int k0 = 0; k0 < K; k0 += 64) {
#pragma unroll
        for (int p = 0; p < 4; p++) {
            int idx = tid + p * 256;
            *(f16x8*)&sAh[idx >> 3][(idx & 7) * 8] = pA[p];
        }
#pragma unroll
        for (int p = 0; p < 2; p++) {
            int idx = tid + p * 256;
            *(f16x8*)&sBh[idx >> 3][(idx & 7) * 8] = pB[p];
        }
        __syncthreads();

        if (k0 + 64 < K) {
            int kn = k0 + 64;
#pragma unroll
            for (int p = 0; p < 4; p++) {
                int idx = tid + p * 256;
                int r = idx >> 3, ch = (idx & 7) * 8;
                int gr = row0 + r;
                pA[p] = (gr < nrow) ? *(const f16x8*)(Ah + (long)gr * K + kn + ch) : (f16x8)0;
            }
#pragma unroll
            for (int p = 0; p < 2; p++) {
                int idx = tid + p * 256;
                int r = idx >> 3, ch = (idx & 7) * 8;
                pB[p] = *(const f16x8*)(Bh + (long)(col0 + r) * K + kn + ch);
            }
        }

#pragma unroll
        for (int sub = 0; sub < 2; sub++) {
            const int fks = fk + sub * 32;
            f16x8 bh[2];
#pragma unroll
            for (int nt = 0; nt < 2; nt++)
                bh[nt] = *(const f16x8*)&sBh[wn * 32 + nt * 16 + frow][fks];
#pragma unroll
            for (int mt = 0; mt < 4; mt++) {
                f16x8 ah = *(const f16x8*)&sAh[wm * 64 + mt * 16 + frow][fks];
#pragma unroll
                for (int nt = 0; nt < 2; nt++)
                    acc[mt][nt] = __builtin_amdgcn_mfma_f32_16x16x32_f16(ah, bh[nt], acc[mt][nt], 0, 0, 0);
            }
        }
        __syncthreads();
    }

    const int crow0 = row0 + wm * 64 + (lane >> 4) * 4;
    const int ccol0 = col0 + wn * 32 + (lane & 15);

    if (mode == 0) {
#pragma unroll
        for (int mt = 0; mt < 4; mt++)
#pragma unroll
            for (int nt = 0; nt < 2; nt++) {
                int col = ccol0 + nt * 16;
#pragma unroll
                for (int r = 0; r < 4; r++) {
                    int row = crow0 + mt * 16 + r;
                    if (row < nrow) Ch[(long)row * 256 + col] = (_Float16)acc[mt][nt][r];
                }
            }
        // fused a_s/a_d from fp32 acc regs (C=32 layers): plain stores.
        if (asl != nullptr) {
            const float asl0 = asl[ccol0], asl1 = asl[ccol0 + 16];
            const float adl0 = adl[ccol0], adl1 = adl[ccol0 + 16];
            const int headw = (col0 + wn * 32) >> 5;
#pragma unroll
            for (int mt = 0; mt < 4; mt++) {
#pragma unroll
                for (int r = 0; r < 4; r++) {
                    float s = acc[mt][0][r] * asl0 + acc[mt][1][r] * asl1;
                    float d = acc[mt][0][r] * adl0 + acc[mt][1][r] * adl1;
                    s += __shfl_xor(s, 1); s += __shfl_xor(s, 2);
                    s += __shfl_xor(s, 4); s += __shfl_xor(s, 8);
                    d += __shfl_xor(d, 1); d += __shfl_xor(d, 2);
                    d += __shfl_xor(d, 4); d += __shfl_xor(d, 8);
                    if ((lane & 15) == 0) {
                        int row = crow0 + mt * 16 + r;
                        if (row < nrow) {
                            asb[row * 8 + headw] = s;
                            adb[row * 8 + headw] = d;
                        }
                    }
                }
            }
        }
    } else {
        // mode 3: gelu(v+bias) -> per-graph pooled sums, register pre-accum (R11).
        float* pool = (float*)&sAh[0][0];            // 16*64 floats = 4KB
        const int g0 = batch[row0];
        const int rlast = (row0 + 127 < nrow) ? row0 + 127 : nrow - 1;
        const int gspan = batch[rlast] - g0 + 1;
        const bool fits = (gspan <= 16);
        for (int i = tid; i < 16 * 64; i += 256) pool[i] = 0.f;
        __syncthreads();

        const float b0 = bias[ccol0], b1 = bias[ccol0 + 16];
        const int lc0 = ccol0 - col0, lc1 = lc0 + 16;
        float sum0 = 0.f, sum1 = 0.f;
        int curg = -1;
#pragma unroll
        for (int mt = 0; mt < 4; mt++) {
#pragma unroll
            for (int r = 0; r < 4; r++) {
                int row = crow0 + mt * 16 + r;
                if (row >= nrow) continue;
                int g = batch[row];
                if (g != curg) {
                    if (curg >= 0) {
                        if (fits) {
                            atomicAdd(&pool[(curg - g0) * 64 + lc0], sum0);
                            atomicAdd(&pool[(curg - g0) * 64 + lc1], sum1);
                        } else {
                            atomicAdd(&pooled[curg * 256 + ccol0], sum0);
                            atomicAdd(&pooled[curg * 256 + ccol0 + 16], sum1);
                        }
                    }
                    curg = g; sum0 = 0.f; sum1 = 0.f;
                }
                float v0 = acc[mt][0][r] + b0;
                float v1 = acc[mt][1][r] + b1;
                sum0 += 0.5f * v0 * (1.f + erff(v0 * 0.7071067811865475f));
                sum1 += 0.5f * v1 * (1.f + erff(v1 * 0.7071067811865475f));
            }
        }
        if (curg >= 0) {
            if (fits) {
                atomicAdd(&pool[(curg - g0) * 64 + lc0], sum0);
                atomicAdd(&pool[(curg - g0) * 64 + lc1], sum1);
            } else {
                atomicAdd(&pooled[curg * 256 + ccol0], sum0);
                atomicAdd(&pooled[curg * 256 + ccol0 + 16], sum1);
            }
        }
        __syncthreads();
        if (fits) {
            for (int i = tid; i < gspan * 64; i += 256) {
                float val = pool[i];
                if (val != 0.f)
                    atomicAdd(&pooled[(g0 + (i >> 6)) * 256 + col0 + (i & 63)], val);
            }
        }
    }
}

// ================= single prep kernel =================
#define J0 1600000                       // x convert (float4 units): N*DIN/4
#define J1 32768                         // W1 transpose (256 x 128)
#define J2 65536                         // W2
#define J3 65536                         // W3
#define J4 65536                         // fcW1
#define J5 16384                         // zero pooled (64*256)
#define J6 N_NODES                       // zero deg
#define J7 64                            // zero gcnt
#define JTOT (J0+J1+J2+J3+J4+J5+J6+J7)

__device__ __forceinline__ void t_one(const float* W, _Float16* Bh,
                                      int id, int K, int realN)
{
    int n = id / K, k = id - n * K;
    Bh[id] = (_Float16)W[(long)k * realN + n];
}

__global__ __launch_bounds__(256) void prep_kernel(
    const float* __restrict__ x,
    const float* __restrict__ W1, const float* __restrict__ W2, const float* __restrict__ W3,
    const float* __restrict__ F1,
    _Float16* __restrict__ xh,
    _Float16* __restrict__ W1th, _Float16* __restrict__ W2th,
    _Float16* __restrict__ W3th, _Float16* __restrict__ F1th,
    float* __restrict__ pooled, int* __restrict__ deg, int* __restrict__ gcnt)
{
    int idx = blockIdx.x * 256 + threadIdx.x;
    if (idx < J0) {
        float4 v = ((const float4*)x)[idx];
        f16x4 h;
        h[0] = (_Float16)v.x; h[1] = (_Float16)v.y;
        h[2] = (_Float16)v.z; h[3] = (_Float16)v.w;
        *(f16x4*)(xh + (long)idx * 4) = h;
        return;
    }
    idx -= J0;
    if (idx < J1) { t_one(W1, W1th, idx, DIN, NHC); return; }
    idx -= J1;
    if (idx < J2) { t_one(W2, W2th, idx, NHC, NHC); return; }
    idx -= J2;
    if (idx < J3) { t_one(W3, W3th, idx, NHC, NHC); return; }
    idx -= J3;
    if (idx < J4) { t_one(F1, F1th, idx, NHC, NHC); return; }
    idx -= J4;
    if (idx < J5) { pooled[idx] = 0.f; return; }
    idx -= J5;
    if (idx < J6) { deg[idx] = 0; return; }
    idx -= J6;
    if (idx < J7) { gcnt[idx] = 0; return; }
}

// -------- all 3 layers' Me[5][H] in one launch --------
__global__ void me_all_kernel(
    const float* __restrict__ We1, const float* __restrict__ ae1,
    const float* __restrict__ We2, const float* __restrict__ ae2,
    const float* __restrict__ We3, const float* __restrict__ ae3,
    float* __restrict__ MeAll)
{
    int l = blockIdx.x;
    const float* We = (l == 0) ? We1 : (l == 1) ? We2 : We3;
    const float* ae = (l == 0) ? ae1 : (l == 1) ? ae2 : ae3;
    int H = (l == 2) ? 1 : 8, C = (l == 2) ? 256 : 32;
    int t = threadIdx.x;
    if (t >= 5 * H) return;
    int j = t / H, hh = t - j * H;
    float s = 0.f;
    for (int c = 0; c < C; c++) s += We[j * NHC + hh * C + c] * ae[hh * C + c];
    MeAll[l * 40 + j * H + hh] = s;
}

// -------- asd (layer 3 only: H=1, C=256), fp16 h --------
__global__ __launch_bounds__(256) void asd_kernel(
    const _Float16* __restrict__ h, const float* __restrict__ atts, const float* __restrict__ attd,
    float* __restrict__ asb, float* __restrict__ adb, int total)
{
    int n = blockIdx.x * 256 + threadIdx.x;
    if (n >= total) return;
    const f16x8* hp = (const f16x8*)(h + (long)n * NHC);
    const float4* sp = (const float4*)atts;
    const float4* dp = (const float4*)attd;
    float ss = 0.f, dd = 0.f;
    for (int c = 0; c < NHC / 8; c++) {
        f16x8 hv = hp[c];
        float4 s1 = sp[2 * c], s2 = sp[2 * c + 1];
        float4 d1 = dp[2 * c], d2 = dp[2 * c + 1];
        ss += (float)hv[0] * s1.x + (float)hv[1] * s1.y + (float)hv[2] * s1.z + (float)hv[3] * s1.w
            + (float)hv[4] * s2.x + (float)hv[5] * s2.y + (float)hv[6] * s2.z + (float)hv[7] * s2.w;
        dd += (float)hv[0] * d1.x + (float)hv[1] * d1.y + (float)hv[2] * d1.z + (float)hv[3] * d1.w
            + (float)hv[4] * d2.x + (float)hv[5] * d2.y + (float)hv[6] * d2.z + (float)hv[7] * d2.w;
    }
    asb[n * 8] = ss; adb[n * 8] = dd;
}

// ================= CSR build =================
__global__ __launch_bounds__(256) void count_hist_kernel(
    const int* __restrict__ ei, const int* __restrict__ batch,
    int* __restrict__ deg, int* __restrict__ gcnt, int E, int N)
{
    __shared__ int hist[N_GRAPH];
    int t = threadIdx.x;
    if (t < N_GRAPH) hist[t] = 0;
    __syncthreads();
    int i = blockIdx.x * 256 + t;
    if (i < E) atomicAdd(&deg[ei[E + i]], 1);
    if (i < N) atomicAdd(&hist[batch[i]], 1);
    __syncthreads();
    if (t < N_GRAPH && hist[t] > 0) atomicAdd(&gcnt[t], hist[t]);
}

__global__ __launch_bounds__(256) void scan_block_kernel(
    const int* __restrict__ deg, int* __restrict__ rowstart, int* __restrict__ partial, int n)
{
    __shared__ int s[256];
    int i = blockIdx.x * 256 + threadIdx.x;
    int v = (i < n) ? deg[i] : 0;
    s[threadIdx.x] = v;
    __syncthreads();
    for (int off = 1; off < 256; off <<= 1) {
        int t = (threadIdx.x >= off) ? s[threadIdx.x - off] : 0;
        __syncthreads();
        s[threadIdx.x] += t;
        __syncthreads();
    }
    if (i < n) rowstart[i] = s[threadIdx.x] - v;
    if (threadIdx.x == 255) partial[blockIdx.x] = s[255];
}

__global__ __launch_bounds__(256) void scan_partial_kernel(int* __restrict__ partial, int nb)
{
    __shared__ int s[256];
    int v = (threadIdx.x < nb) ? partial[threadIdx.x] : 0;
    s[threadIdx.x] = v;
    __syncthreads();
    for (int off = 1; off < 256; off <<= 1) {
        int t = (threadIdx.x >= off) ? s[threadIdx.x - off] : 0;
        __syncthreads();
        s[threadIdx.x] += t;
        __syncthreads();
    }
    if (threadIdx.x < nb) partial[threadIdx.x] = s[threadIdx.x] - v;
}

__global__ __launch_bounds__(256) void scan_add_kernel(
    int* __restrict__ rowstart, const int* __restrict__ partial, int* __restrict__ cursor,
    int n, int E)
{
    int i = blockIdx.x * 256 + threadIdx.x;
    if (i < n) {
        int v = rowstart[i] + partial[blockIdx.x];
        rowstart[i] = v;
        cursor[i] = v;
    }
    if (i == 0) rowstart[n] = E;
}

// fill: scatter only the 8B (src, e) record; everything else moves to aec_kernel.
__global__ __launch_bounds__(256) void fill_kernel(
    const int* __restrict__ ei, int* __restrict__ cursor, int2* __restrict__ csr2, int E)
{
    int e = blockIdx.x * 256 + threadIdx.x;
    if (e >= E) return;
    int dst = ei[E + e];
    int pos = atomicAdd(&cursor[dst], 1);
    csr2[pos] = make_int2(ei[e], e);
}

// aec: one thread per CSR position (coalesced reads of csr2, coalesced writes
// of csr + all 3 layers' a_e; only the 20B ea gather is scattered -> reads
// pipeline, and ea (8MB) is L2/L3 resident).
__global__ __launch_bounds__(256) void aec_kernel(
    const int2* __restrict__ csr2, const float* __restrict__ ea,
    const float* __restrict__ MeAll,
    int* __restrict__ csr, _Float16* __restrict__ aec, int E)
{
    int pos = blockIdx.x * 256 + threadIdx.x;
    if (pos >= E) return;
    int2 se = csr2[pos];
    csr[pos] = se.x;
    const float* eap = ea + (long)se.y * 5;
    float e0 = eap[0], e1 = eap[1], e2 = eap[2], e3 = eap[3], e4 = eap[4];
#pragma unroll
    for (int l = 0; l < 2; l++) {
        const float* Me = MeAll + l * 40;
        f16x8 v;
#pragma unroll
        for (int hh = 0; hh < 8; hh++) {
            float s = e0 * Me[hh] + e1 * Me[8 + hh] + e2 * Me[16 + hh]
                    + e3 * Me[24 + hh] + e4 * Me[32 + hh];
            v[hh] = (_Float16)s;
        }
        *(f16x8*)(aec + (long)l * N_EDGES * 8 + (long)pos * 8) = v;
    }
    const float* Me2 = MeAll + 80;
    float s2 = e0 * Me2[0] + e1 * Me2[1] + e2 * Me2[2] + e3 * Me2[3] + e4 * Me2[4];
    f16x8 v2;
#pragma unroll
    for (int hh = 0; hh < 8; hh++) v2[hh] = (_Float16)s2;
    *(f16x8*)(aec + (long)2 * N_EDGES * 8 + (long)pos * 8) = v2;
}

// ========== fused GAT aggregation: branch-free, f16x8, 2 edges in flight ====
// wave = 1 node. Phase 1: 8 lanes/edge x 8 edges compute alpha (dups -> pv=0).
// Phase 2: halves (32 lanes) gather f16x8 rows of 2 edges concurrently;
// halves combined once at the end via shfl_xor(32).
__global__ __launch_bounds__(256) void gat_agg_kernel(
    const int* __restrict__ rowstart, const int* __restrict__ csr,
    const _Float16* __restrict__ aec, const float* __restrict__ asb,
    const float* __restrict__ adb,
    const _Float16* __restrict__ h, const float* __restrict__ bias,
    _Float16* __restrict__ Oh, int H, int clog2)
{
    int node = blockIdx.x * 4 + (threadIdx.x >> 6);
    if (node >= N_NODES) return;
    const int lane = threadIdx.x & 63;
    const int half = lane >> 5;        // which edge of the pair
    const int c8   = (lane & 31) * 8;  // this lane's 8-channel group
    const int hc   = c8 >> clog2;      // head owning the group
    const int heff = lane & (H - 1);   // head for alpha compute
    const int grp  = lane >> 3;        // edge slot 0..7 in phase 1

    const float adn = adb[node * 8 + heff];
    const int beg = rowstart[node], end = rowstart[node + 1];

    float acc[8] = {};
    float den = 0.f;

    for (int i = beg; i < end; i += 8) {
        int idx = i + grp;
        const bool valid = (idx < end);
        if (!valid) idx = end - 1;
        const int sj = csr[idx];
        const float ae = (float)aec[(long)idx * 8 + heff];
        float al = asb[sj * 8 + heff] + adn + ae;
        al = fmaxf(al, 0.2f * al);
        const float pv = valid ? __expf(al) : 0.f;
#pragma unroll
        for (int jj = 0; jj < 4; jj++) {
            const int j = jj * 2 + half;
            const float pj = __shfl(pv, j * 8 + hc);
            const int srcj = __shfl(sj, j * 8);
            const f16x8 hv = *(const f16x8*)(h + (long)srcj * NHC + c8);
            den += pj;
#pragma unroll
            for (int k = 0; k < 8; k++)
                acc[k] += pj * (float)hv[k];
        }
    }

    den += __shfl_xor(den, 32);
#pragma unroll
    for (int k = 0; k < 8; k++)
        acc[k] += __shfl_xor(acc[k], 32);

    if (half == 0) {
        const float w = 1.0f / (den + 1e-16f);
        const float4 b0 = *(const float4*)(bias + c8);
        const float4 b1 = *(const float4*)(bias + c8 + 4);
        const float bb[8] = {b0.x, b0.y, b0.z, b0.w, b1.x, b1.y, b1.z, b1.w};
        f16x8 oh;
#pragma unroll
        for (int k = 0; k < 8; k++) {
            float v = acc[k] * w + bb[k];
            v = (v > 0.f) ? v : (__expf(v) - 1.f);   // ELU; fp16 store masks fast-exp err
            oh[k] = (_Float16)v;
        }
        *(f16x8*)(Oh + (long)node * NHC + c8) = oh;
    }
}

// ================= final: out[g,:] = (pooled[g,:]@fcW2)/cnt + fcb2 =================
__global__ void final_kernel(const float* __restrict__ pooled, const int* __restrict__ gcnt,
                             const float* __restrict__ fcW2, const float* __restrict__ fcb2,
                             float* __restrict__ out)
{
    int g = blockIdx.x;
    int j = threadIdx.x;
    if (j >= DOUT) return;
    float s = 0.f;
    for (int k = 0; k < NHC; k++) s += pooled[g * NHC + k] * fcW2[k * DOUT + j];
    int c = gcnt[g];
    out[g * DOUT + j] = (c > 0) ? (s / (float)c + fcb2[j]) : 0.f;
}

extern "C" void kernel_launch(void* const* d_in, const int* in_sizes, int n_in,
                              void* d_out, int out_size, void* d_ws, size_t ws_size,
                              hipStream_t stream)
{
    const float* x    = (const float*)d_in[0];
    const int*   ei   = (const int*)  d_in[1];
    const float* ea   = (const float*)d_in[2];
    const int*   bat  = (const int*)  d_in[3];
    const float* W[3]   = {(const float*)d_in[4],  (const float*)d_in[10], (const float*)d_in[16]};
    const float* Asl[3] = {(const float*)d_in[5],  (const float*)d_in[11], (const float*)d_in[17]};
    const float* Adl[3] = {(const float*)d_in[6],  (const float*)d_in[12], (const float*)d_in[18]};
    const float* Wel[3] = {(const float*)d_in[7],  (const float*)d_in[13], (const float*)d_in[19]};
    const float* Ael[3] = {(const float*)d_in[8],  (const float*)d_in[14], (const float*)d_in[20]};
    const float* Bil[3] = {(const float*)d_in[9],  (const float*)d_in[15], (const float*)d_in[21]};
    const float* fcW1 = (const float*)d_in[22];
    const float* fcb1 = (const float*)d_in[23];
    const float* fcW2 = (const float*)d_in[24];
    const float* fcb2 = (const float*)d_in[25];

    // ---- workspace carve (bytes) ----
    char* w = (char*)d_ws;
    _Float16* h    = (_Float16*)w;     w += (size_t)N_NODES * NHC * 2;   // fp16 h
    _Float16* xh   = (_Float16*)w;     w += (size_t)N_NODES * DIN * 2;
    _Float16* xbh  = (_Float16*)w;     w += (size_t)N_NODES * NHC * 2;
    float*    asb  = (float*)w;        w += (size_t)N_NODES * 8 * 4;
    float*    adb  = (float*)w;        w += (size_t)N_NODES * 8 * 4;
    float*    MeAll= (float*)w;        w += 120 * 4;
    float*    pooled=(float*)w;        w += (size_t)N_GRAPH * NHC * 4;
    _Float16* W1th = (_Float16*)w;     w += (size_t)NHC * DIN * 2;
    _Float16* W2th = (_Float16*)w;     w += (size_t)NHC * NHC * 2;
    _Float16* W3th = (_Float16*)w;     w += (size_t)NHC * NHC * 2;
    _Float16* F1th = (_Float16*)w;     w += (size_t)NHC * NHC * 2;
    int* gcnt     = (int*)w;           w += N_GRAPH * 4;
    int* deg      = (int*)w;           w += (size_t)N_NODES * 4;
    int* rowstart = (int*)w;           w += (size_t)(N_NODES + 1) * 4;
    int* cursor   = (int*)w;           w += (size_t)N_NODES * 4;
    int* partial  = (int*)w;           w += 256 * 4;
    w = (char*)(((size_t)w + 15) & ~(size_t)15);
    int2* csr2    = (int2*)w;          w += (size_t)N_EDGES * 8;
    int* csr      = (int*)w;           w += (size_t)N_EDGES * 4;
    w = (char*)(((size_t)w + 15) & ~(size_t)15);
    _Float16* aec = (_Float16*)w;      w += (size_t)3 * N_EDGES * 8 * 2;  // 19.2 MB

    const int NB = (N_NODES + 255) / 256;

    prep_kernel<<<(JTOT + 255) / 256, 256, 0, stream>>>(
        x, W[0], W[1], W[2], fcW1,
        xh, W1th, W2th, W3th, F1th,
        pooled, deg, gcnt);
    count_hist_kernel<<<(N_EDGES + 255) / 256, 256, 0, stream>>>(ei, bat, deg, gcnt, N_EDGES, N_NODES);
    scan_block_kernel<<<NB, 256, 0, stream>>>(deg, rowstart, partial, N_NODES);
    scan_partial_kernel<<<1, 256, 0, stream>>>(partial, NB);
    scan_add_kernel<<<NB, 256, 0, stream>>>(rowstart, partial, cursor, N_NODES, N_EDGES);
    me_all_kernel<<<3, 64, 0, stream>>>(Wel[0], Ael[0], Wel[1], Ael[1], Wel[2], Ael[2], MeAll);
    fill_kernel<<<(N_EDGES + 255) / 256, 256, 0, stream>>>(ei, cursor, csr2, N_EDGES);
    aec_kernel<<<(N_EDGES + 255) / 256, 256, 0, stream>>>(csr2, ea, MeAll, csr, aec, N_EDGES);

    const int Hs[3] = {8, 8, 1};
    const int CL[3] = {5, 5, 8};
    const int Ks[3] = {DIN, NHC, NHC};

    const dim3 ggrid(4, 392);

    const _Float16* curh = xh;
    const _Float16* Wth[3] = {W1th, W2th, W3th};
    for (int l = 0; l < 3; l++) {
        const int H = Hs[l];
        const bool fuse = (l != 2);
        mfma_gemm_kernel<<<ggrid, 256, 0, stream>>>(
            curh, Wth[l], nullptr, h,
            fuse ? Asl[l] : nullptr, fuse ? Adl[l] : nullptr, asb, adb,
            nullptr, nullptr,
            N_NODES, Ks[l], 0);
        if (!fuse)
            asd_kernel<<<(N_NODES + 255) / 256, 256, 0, stream>>>(
                h, Asl[l], Adl[l], asb, adb, N_NODES);
        gat_agg_kernel<<<(N_NODES + 3) / 4, 256, 0, stream>>>(
            rowstart, csr, aec + (size_t)l * N_EDGES * 8, asb, adb, h, Bil[l], xbh, H, CL[l]);
        curh = xbh;
    }

    // fc1 + fused gelu + per-graph pooling (fc2 commutes with pooling)
    mfma_gemm_kernel<<<ggrid, 256, 0, stream>>>(
        xbh, F1th, fcb1, nullptr,
        nullptr, nullptr, nullptr, nullptr,
        bat, pooled,
        N_NODES, NHC, 3);
    final_kernel<<<N_GRAPH, 64, 0, stream>>>(pooled, gcnt, fcW2, fcb2, (float*)d_out);
}